// Round 1
// baseline (255.450 us; speedup 1.0000x reference)
//
#include <hip/hip_runtime.h>

#define H_IMG 512
#define W_IMG 512
#define PLANES 96                  // 32 * 3
#define NPIX 25165824.0            // 96 * 512 * 512

#define TW 64
#define TH 32
#define HALO 5
#define IW (TW + 2 * HALO)         // 74
#define IH (TH + 2 * HALO)         // 42
#define LSTR 76                    // padded LDS stride (multiple of 4 -> float4 aligned)
#define TILES_X (W_IMG / TW)       // 8
#define TILES_Y (H_IMG / TH)       // 16

__global__ void ssim_zero(double* acc) {
    if (threadIdx.x == 0) acc[0] = 0.0;
}

__global__ void ssim_final(const double* __restrict__ acc, float* __restrict__ out) {
    if (threadIdx.x == 0) out[0] = (float)(1.0 - acc[0] / NPIX);
}

__global__ void ssim_main(const float* __restrict__ img1,
                          const float* __restrict__ img2,
                          double* __restrict__ acc)
{
    // normalized 11-tap Gaussian, sigma=1.5 (matches reference _create_window)
    constexpr float G[11] = {
        0.00102838f, 0.00759875f, 0.03600077f, 0.10936070f, 0.21300540f,
        0.26601180f,
        0.21300540f, 0.10936070f, 0.03600077f, 0.00759875f, 0.00102838f };
    constexpr float C1 = 0.0001f;   // (0.01*1.0)^2
    constexpr float C2 = 0.0009f;   // (0.03*1.0)^2

    __shared__ float s1[IH][LSTR];
    __shared__ float s2[IH][LSTR];
    __shared__ __align__(16) float sv[5][TH][LSTR];
    __shared__ float wsum[4];

    const int tid   = threadIdx.x;
    const int tile  = blockIdx.x;    // 0..127
    const int plane = blockIdx.y;    // 0..95
    const int col0 = (tile % TILES_X) * TW;
    const int row0 = (tile / TILES_X) * TH;
    const float* __restrict__ p1 = img1 + (size_t)plane * (H_IMG * W_IMG);
    const float* __restrict__ p2 = img2 + (size_t)plane * (H_IMG * W_IMG);

    // ---- stage 0: global -> LDS tile + zero-padded halo ----
    for (int i = tid; i < IH * IW; i += 256) {
        const int r = i / IW;
        const int c = i - r * IW;
        const int gr = row0 - HALO + r;
        const int gc = col0 - HALO + c;
        float a = 0.f, b = 0.f;
        if ((unsigned)gr < (unsigned)H_IMG && (unsigned)gc < (unsigned)W_IMG) {
            const int off = gr * W_IMG + gc;
            a = p1[off];
            b = p2[off];
        }
        s1[r][c] = a;
        s2[r][c] = b;
    }
    __syncthreads();

    // ---- stage 1: vertical 11-tap conv on 5 derived channels ----
    // task = one column, 4 consecutive output rows (register-blocked)
    for (int t = tid; t < (TH / 4) * IW; t += 256) {
        const int c  = t % IW;
        const int r0 = (t / IW) * 4;
        float x1[14], x2[14], q11[14], q22[14], q12[14];
        #pragma unroll
        for (int j = 0; j < 14; ++j) {
            const float u = s1[r0 + j][c];
            const float v = s2[r0 + j][c];
            x1[j] = u;  x2[j] = v;
            q11[j] = u * u;  q22[j] = v * v;  q12[j] = u * v;
        }
        #pragma unroll
        for (int i = 0; i < 4; ++i) {
            float m1 = 0.f, m2 = 0.f, e11 = 0.f, e22 = 0.f, e12 = 0.f;
            #pragma unroll
            for (int k = 0; k < 11; ++k) {
                m1  = fmaf(G[k], x1[i + k],  m1);
                m2  = fmaf(G[k], x2[i + k],  m2);
                e11 = fmaf(G[k], q11[i + k], e11);
                e22 = fmaf(G[k], q22[i + k], e22);
                e12 = fmaf(G[k], q12[i + k], e12);
            }
            sv[0][r0 + i][c] = m1;
            sv[1][r0 + i][c] = m2;
            sv[2][r0 + i][c] = e11;
            sv[3][r0 + i][c] = e22;
            sv[4][r0 + i][c] = e12;
        }
    }
    __syncthreads();

    // ---- stage 2: horizontal 11-tap conv (float4 LDS reads) + SSIM ----
    float lsum = 0.f;
    for (int t = tid; t < TH * (TW / 4); t += 256) {
        const int c0 = (t % (TW / 4)) * 4;   // output cols c0..c0+3
        const int r  = t / (TW / 4);
        float res[5][4];
        #pragma unroll
        for (int ch = 0; ch < 5; ++ch) {
            float w[16];
            const float4* s = (const float4*)(&sv[ch][r][c0]);
            const float4 t0 = s[0], t1 = s[1], t2 = s[2], t3 = s[3];
            w[0]=t0.x;  w[1]=t0.y;  w[2]=t0.z;  w[3]=t0.w;
            w[4]=t1.x;  w[5]=t1.y;  w[6]=t1.z;  w[7]=t1.w;
            w[8]=t2.x;  w[9]=t2.y;  w[10]=t2.z; w[11]=t2.w;
            w[12]=t3.x; w[13]=t3.y; w[14]=t3.z; w[15]=t3.w;
            #pragma unroll
            for (int i = 0; i < 4; ++i) {
                float acc5 = 0.f;
                #pragma unroll
                for (int k = 0; k < 11; ++k)
                    acc5 = fmaf(G[k], w[i + k], acc5);
                res[ch][i] = acc5;
            }
        }
        #pragma unroll
        for (int i = 0; i < 4; ++i) {
            const float mu1 = res[0][i], mu2 = res[1][i];
            const float mu1s = mu1 * mu1, mu2s = mu2 * mu2, mu12 = mu1 * mu2;
            const float v11 = fmaxf(res[2][i] - mu1s, 0.f);
            const float v22 = fmaxf(res[3][i] - mu2s, 0.f);
            const float v12 = res[4][i] - mu12;
            const float num = (2.f * mu12 + C1) * (2.f * v12 + C2);
            const float den = (mu1s + mu2s + C1) * (v11 + v22 + C2);
            lsum += num / den;
        }
    }

    // ---- block reduce + one device-scope atomic per block ----
    #pragma unroll
    for (int off = 32; off > 0; off >>= 1)
        lsum += __shfl_down(lsum, off, 64);
    const int wave = tid >> 6, lane = tid & 63;
    if (lane == 0) wsum[wave] = lsum;
    __syncthreads();
    if (tid == 0)
        atomicAdd(acc, (double)(wsum[0] + wsum[1] + wsum[2] + wsum[3]));
}

extern "C" void kernel_launch(void* const* d_in, const int* in_sizes, int n_in,
                              void* d_out, int out_size, void* d_ws, size_t ws_size,
                              hipStream_t stream) {
    const float* img1 = (const float*)d_in[0];
    const float* img2 = (const float*)d_in[1];
    float* out  = (float*)d_out;
    double* acc = (double*)d_ws;

    ssim_zero<<<dim3(1), dim3(64), 0, stream>>>(acc);
    ssim_main<<<dim3(TILES_X * TILES_Y, PLANES), dim3(256), 0, stream>>>(img1, img2, acc);
    ssim_final<<<dim3(1), dim3(64), 0, stream>>>(acc, out);
}